// Round 4
// baseline (775.066 us; speedup 1.0000x reference)
//
#include <hip/hip_runtime.h>
#include <hip/hip_bf16.h>

#define M_DIM 4096
#define N_DIM 8192
#define K_DIM 8192

using bf16x8 = __attribute__((ext_vector_type(8))) short;
using f32x4  = __attribute__((ext_vector_type(4))) float;
using f32x16 = __attribute__((ext_vector_type(16))) float;

static __device__ __forceinline__ unsigned short f32_to_bf16_rne(float f) {
    unsigned u = __float_as_uint(f);
    unsigned rounding = 0x7FFFu + ((u >> 16) & 1u);
    u += rounding;
    return (unsigned short)(u >> 16);
}

// ---------------- zero W (f32) ----------------
__global__ void zero_kernel(float4* __restrict__ p, int n4) {
    int i = blockIdx.x * blockDim.x + threadIdx.x;
    int stride = gridDim.x * blockDim.x;
    float4 z = make_float4(0.f, 0.f, 0.f, 0.f);
    for (; i < n4; i += stride) p[i] = z;
}

// ---------------- scatter-add COO ----------------
__global__ void scatter_kernel(const float* __restrict__ vals,
                               const int* __restrict__ rows,
                               const int* __restrict__ cols,
                               float* __restrict__ W, int n) {
    int i = blockIdx.x * blockDim.x + threadIdx.x;
    if (i < n) {
        atomicAdd(&W[(size_t)rows[i] * K_DIM + cols[i]], vals[i]);
    }
}

// ---------------- f32 -> bf16 cast ----------------
__global__ void cvt_bf16_kernel(const float4* __restrict__ src,
                                ushort4* __restrict__ dst, int n4) {
    int i = blockIdx.x * blockDim.x + threadIdx.x;
    int stride = gridDim.x * blockDim.x;
    for (; i < n4; i += stride) {
        float4 v = src[i];
        ushort4 o;
        o.x = f32_to_bf16_rne(v.x);
        o.y = f32_to_bf16_rne(v.y);
        o.z = f32_to_bf16_rne(v.z);
        o.w = f32_to_bf16_rne(v.w);
        dst[i] = o;
    }
}

// ---------------- zero d_out fallback (ws too small diagnostic) ----------------
__global__ void zero_out_kernel(float* __restrict__ p, int n) {
    int i = blockIdx.x * blockDim.x + threadIdx.x;
    int stride = gridDim.x * blockDim.x;
    for (; i < n; i += stride) p[i] = 0.f;
}

// ---------------- bf16 NT GEMM, 256x256 8-phase, 32x32x16 MFMA ----------------
// C[M][N] = A[M][K] * B[N][K]^T.  BM=BN=256, BK=64, 8 waves (2M x 4N),
// per-wave output 128x64 as acc[4 mfrag][2 nfrag] f32x16.  LDS 128 KiB
// double-buffered: [db][A/B][half 128 rows][128][64] bf16.
// Phase = K-step s (4 per tile): {ds_read af[4] (+8 B frags at s=0, B is
// register-resident for the whole tile) | stage 1 half-tile | barrier |
// lgkmcnt(0) | setprio(1) 8 independent 32x32x16 MFMA setprio(0) |
// (boundary vmcnt) | barrier}.  Staging (liveness unchanged from r2):
//   s0: A(t+1) h0 -> db^1   s1: A(t+1) h1 -> db^1
//   s2: B(t+2) h0 -> db     s3: B(t+2) h1 -> db   (B[db] dead after s0)
// Boundary vmcnt(4) leaves exactly the B(t+2) pair in flight (T4).
// LDS swizzle (T2, rule #21): slot (row,c) holds global k-chunk c^(row&7);
// staging pre-swizzles the global source, reads apply the same involution.
// Bank check: byte = row*128 + sc*16 -> quad = sc; wave covers 8 quads x 8
// lanes = conflict-free b128 minimum.
// 32x32x16 frag layout: A lane l, reg j = A[row=l&31][k=(l>>5)*8+j]; B
// symmetric; C/D col=lane&31, row=(reg&3)+8*(reg>>2)+4*(lane>>5) [m74/m101].
__global__ __launch_bounds__(512, 2) void gemm_bt(const ushort* __restrict__ A,
                                                  const ushort* __restrict__ B,
                                                  float* __restrict__ C) {
    constexpr int BK = 64;
    constexpr int NT = K_DIM / BK;     // 128 K-tiles
    __shared__ ushort lds[65536];      // 128 KiB

    const int nbn = N_DIM / 256;       // 32
    const int bm = blockIdx.x / nbn;
    const int bn = blockIdx.x % nbn;
    const int brow = bm * 256, bcol = bn * 256;

    const int t    = threadIdx.x;
    const int lane = t & 63;
    const int wid  = t >> 6;           // 0..7
    const int wm   = wid >> 2;         // 0..1 (M half)
    const int wn   = wid & 3;          // 0..3 (N quarter)
    const int lr32 = lane & 31;        // row/col within 32x32 frag
    const int ghi  = lane >> 5;        // 0..1 (k-half of frag)
    const int sx   = lane & 7;         // read-side swizzle XOR (row&7 == lane&7)

    f32x16 acc[4][2] = {};
    bf16x8 bfr[2][4];                  // B frags [nfrag][kstep], tile-resident

    // stage one 128x64 half-tile: 512 thr x 2 x 16B. Linear LDS dest,
    // source k-chunk pre-swizzled: (fl&7) ^ ((fl>>3)&7).
    auto stage_half = [&](int db, int op, int half, int ktile) {
        const ushort* G = (op == 0) ? A : B;
        const int rbase = ((op == 0) ? brow : bcol) + half * 128;
        #pragma unroll
        for (int i = 0; i < 2; ++i) {
            int fl  = i * 512 + t;                 // 0..1023
            int row = fl >> 3;
            int cc  = (fl & 7) ^ (row & 7);
            const ushort* src = G + (size_t)(rbase + row) * K_DIM + ktile * BK + cc * 8;
            __builtin_amdgcn_global_load_lds(
                (const __attribute__((address_space(1))) void*)src,
                (__attribute__((address_space(3))) void*)
                    (&lds[db * 32768 + op * 16384 + half * 8192 + fl * 8]),
                16, 0, 0);
        }
    };

    auto tile_body = [&](int tt, int db, bool stgA, bool stgB, int vm) {
        // per-wave LDS bases (element offsets into ushort lds[])
        const ushort* Ah = &lds[db * 32768 + wm * 8192];
        const ushort* Bh = &lds[db * 32768 + 16384 + (wn >> 1) * 8192 + (wn & 1) * 4096];
        #pragma unroll
        for (int s = 0; s < 4; ++s) {
            const int sc = (2 * s + ghi) ^ sx;     // swizzled k-chunk this step
            bf16x8 af[4];
            if (s == 0) {
                #pragma unroll
                for (int n = 0; n < 2; ++n)
                    #pragma unroll
                    for (int ss = 0; ss < 4; ++ss) {
                        const int scb = (2 * ss + ghi) ^ sx;
                        bfr[n][ss] = *(const bf16x8*)(Bh + (n * 32 + lr32) * 64 + scb * 8);
                    }
            }
            #pragma unroll
            for (int m = 0; m < 4; ++m)
                af[m] = *(const bf16x8*)(Ah + (m * 32 + lr32) * 64 + sc * 8);

            if (s == 0 && stgA) stage_half(db ^ 1, 0, 0, tt + 1);
            if (s == 1 && stgA) stage_half(db ^ 1, 0, 1, tt + 1);
            if (s == 2 && stgB) stage_half(db,     1, 0, tt + 2);
            if (s == 3 && stgB) stage_half(db,     1, 1, tt + 2);
            __builtin_amdgcn_s_barrier();
            asm volatile("s_waitcnt lgkmcnt(0)" ::: "memory");
            __builtin_amdgcn_s_setprio(1);
            #pragma unroll
            for (int m = 0; m < 4; ++m)
                #pragma unroll
                for (int n = 0; n < 2; ++n)
                    acc[m][n] = __builtin_amdgcn_mfma_f32_32x32x16_bf16(
                        af[m], bfr[n][s], acc[m][n], 0, 0, 0);
            __builtin_amdgcn_s_setprio(0);
            if (s == 3) {
                if (vm == 4) asm volatile("s_waitcnt vmcnt(4)" ::: "memory");
                else         asm volatile("s_waitcnt vmcnt(0)" ::: "memory");
            }
            __builtin_amdgcn_s_barrier();
        }
    };

    // ---- prologue: tile 0 fully + B(1); drain to 4 (B(1) stays in flight) ----
    stage_half(0, 0, 0, 0);
    stage_half(0, 0, 1, 0);
    stage_half(0, 1, 0, 0);
    stage_half(0, 1, 1, 0);
    stage_half(1, 1, 0, 1);
    stage_half(1, 1, 1, 1);
    asm volatile("s_waitcnt vmcnt(4)" ::: "memory");
    __builtin_amdgcn_s_barrier();

    // ---- main loop: tiles 0..NT-3 with full staging, vmcnt(4) ----
    for (int tt = 0; tt < NT - 2; tt += 2) {
        tile_body(tt,     0, true, true, 4);
        tile_body(tt + 1, 1, true, true, 4);
    }
    // ---- peeled tail: NT-2 stages A(NT-1) only then drains; NT-1 bare ----
    tile_body(NT - 2, 0, true,  false, 0);
    tile_body(NT - 1, 1, false, false, 0);

    // ---- epilogue: C/D col=lane&31, row=(reg&3)+8*(reg>>2)+4*(lane>>5) ----
    #pragma unroll
    for (int m = 0; m < 4; ++m) {
        #pragma unroll
        for (int n = 0; n < 2; ++n) {
            const int col   = bcol + wn * 64 + n * 32 + lr32;
            const int rbase = brow + wm * 128 + m * 32 + 4 * ghi;
            #pragma unroll
            for (int r = 0; r < 16; ++r) {
                int row = rbase + (r & 3) + 8 * (r >> 2);
                C[(size_t)row * N_DIM + col] = acc[m][n][r];
            }
        }
    }
}

extern "C" void kernel_launch(void* const* d_in, const int* in_sizes, int n_in,
                              void* d_out, int out_size, void* d_ws, size_t ws_size,
                              hipStream_t stream) {
    const float* x    = (const float*)d_in[0];
    const float* vals = (const float*)d_in[1];
    const int* rows   = (const int*)d_in[2];
    const int* cols   = (const int*)d_in[3];
    float* out        = (float*)d_out;
    const int n_items = in_sizes[1];

    const size_t W_F32_BYTES  = (size_t)N_DIM * K_DIM * 4;  // 256 MiB
    const size_t W_BF16_BYTES = (size_t)N_DIM * K_DIM * 2;  // 128 MiB
    const size_t X_BF16_BYTES = (size_t)M_DIM * K_DIM * 2;  //  64 MiB
    const size_t NEEDED = W_F32_BYTES + W_BF16_BYTES + X_BF16_BYTES;

    if (ws_size < NEEDED) {
        // Diagnostic fallback: clean absmax=126 failure signals ws too small.
        zero_out_kernel<<<2048, 256, 0, stream>>>(out, out_size);
        return;
    }

    char* ws = (char*)d_ws;
    float* Wf  = (float*)ws;
    ushort* Wb = (ushort*)(ws + W_F32_BYTES);
    ushort* Xb = (ushort*)(ws + W_F32_BYTES + W_BF16_BYTES);

    // 1) zero W (re-zeroed every call: deterministic under replay)
    zero_kernel<<<2048, 256, 0, stream>>>((float4*)Wf, (N_DIM * K_DIM) / 4);
    // 2) scatter-add nonzeros
    scatter_kernel<<<(n_items + 255) / 256, 256, 0, stream>>>(vals, rows, cols, Wf, n_items);
    // 3) cast W and x to bf16
    cvt_bf16_kernel<<<2048, 256, 0, stream>>>((const float4*)Wf, (ushort4*)Wb,
                                              (N_DIM * K_DIM) / 4);
    cvt_bf16_kernel<<<2048, 256, 0, stream>>>((const float4*)x, (ushort4*)Xb,
                                              (M_DIM * K_DIM) / 4);
    // 4) GEMM: out = Xb (M x K) * Wb (N x K)^T  -- 512 blocks of 512 threads
    gemm_bt<<<(M_DIM / 256) * (N_DIM / 256), 512, 0, stream>>>(Xb, Wb, out);
}